// Round 1
// baseline (25644.003 us; speedup 1.0000x reference)
//
#include <hip/hip_runtime.h>
#include <math.h>

#define B 64
#define P 196
#define ENCD 512
#define DECD 512
#define EMBD 256
#define ATTD 128
#define FFND 1024
#define VV 2000
#define MAXLEN 160
#define TSTEPS 159

// output chunk offsets (flat f32)
#define OUT_PRED ((size_t)0)
#define OUT_CAPS ((size_t)(B * TSTEPS * VV))            // 20352000
#define OUT_DECL (OUT_CAPS + (size_t)(B * MAXLEN))      // 20362240
#define OUT_ALPH (OUT_DECL + (size_t)B)                 // 20362304
#define OUT_ORDR (OUT_ALPH + (size_t)(B * TSTEPS * P))  // 22355840

struct Ctx {
  // inputs
  const float* enc; const int* caps_in; const int* lens_in;
  const float* enc_att_b; const float* dec_att_b;
  const float* full_att_w; const float* full_att_b;
  const float* gate_b1; const float* gate_w2; const float* gate_b2;
  const float* emb;
  const float* bih1; const float* bhh1; const float* bih2; const float* bhh2;
  const float* proj_b; const float* ln1g; const float* ln1b; const float* ln2g; const float* ln2b;
  const float* fb1; const float* fb2;
  // ws
  int* order_i; int* caps_s; int* declen;
  float* EaT; float* att1;
  float* h1; float* h2; float* h2res; float* h1res;
  float* att2g1; float* gate; float* alpha; float* gin;
  float* f_p; float* preds_p; float* gh1_p; float* gh2_p; float* giP_p; float* gi2_p;
  float* out;
  int t;
};

struct MMJob {
  const float* X; const float* Xaux; const float* Wt; float* outp;
  int Dld; int Kstr; int k0; int kcl; int bx0; int nbx; int mode;
};
struct MMTable { int n; MMJob j[12]; };

// generic partial GEMM: out[b, d(+1)] = sum_{k in [k0,k0+kc)} X[b,k] * Wt[k, d]
// block: 256 threads, covers 512 d-columns x 8 batch rows. No bias (added by consumers).
__device__ __forceinline__ void mm_body(const MMJob& jb, int bx, float* Xs) {
  int tid = threadIdx.x;
  int rel = bx - jb.bx0;
  int jx = rel % jb.nbx;
  int jy = rel / jb.nbx;
  int b0 = jy * 8;
  int d = jx * 512 + tid * 2;
  int kc = 1 << jb.kcl;
  for (int idx = tid; idx < (8 << jb.kcl); idx += 256) {
    int bb = idx >> jb.kcl;
    int k = idx & (kc - 1);
    float v;
    if (jb.mode == 0) {
      v = jb.X[(size_t)(b0 + bb) * jb.Kstr + jb.k0 + k];
    } else {  // mode 1: f = relu(f_p0 + f_p1 + ffn_b1) staged on the fly
      size_t r = (size_t)(b0 + bb) * 1024 + jb.k0 + k;
      v = jb.X[r] + jb.X[(size_t)64 * 1024 + r] + jb.Xaux[jb.k0 + k];
      v = fmaxf(v, 0.0f);
    }
    Xs[idx] = v;
  }
  __syncthreads();
  const float* wp = jb.Wt + (size_t)jb.k0 * jb.Dld + d;
  float a0[8], a1[8];
#pragma unroll
  for (int bb = 0; bb < 8; ++bb) { a0[bb] = 0.f; a1[bb] = 0.f; }
  for (int k = 0; k < kc; k += 4) {
    float2 w0 = *(const float2*)(wp);
    float2 w1 = *(const float2*)(wp + jb.Dld);
    float2 w2 = *(const float2*)(wp + 2 * jb.Dld);
    float2 w3 = *(const float2*)(wp + 3 * jb.Dld);
    wp += 4 * (size_t)jb.Dld;
#pragma unroll
    for (int bb = 0; bb < 8; ++bb) {
      float4 x = *(const float4*)(Xs + bb * kc + k);
      a0[bb] += w0.x * x.x + w1.x * x.y + w2.x * x.z + w3.x * x.w;
      a1[bb] += w0.y * x.x + w1.y * x.y + w2.y * x.z + w3.y * x.w;
    }
  }
#pragma unroll
  for (int bb = 0; bb < 8; ++bb) {
    *(float2*)(jb.outp + (size_t)(b0 + bb) * jb.Dld + d) = make_float2(a0[bb], a1[bb]);
  }
}

__global__ __launch_bounds__(256) void mm_phase(MMTable tab) {
  extern __shared__ float Xs[];
  int bx = blockIdx.x;
  int ji = 0;
  for (int i = 1; i < tab.n; ++i)
    if (bx >= tab.j[i].bx0) ji = i;
  mm_body(tab.j[ji], bx, Xs);
}

// blocks 0..63: per-b attention (gate, e, softmax, alpha); blocks >=64: preds partial GEMM (step t-1)
__global__ __launch_bounds__(256) void attn_preds(Ctx c, MMTable tab) {
  extern __shared__ float smem[];
  int bx = blockIdx.x;
  int tid = threadIdx.x;
  if (bx >= 64) {
    int ji = 0;
    for (int i = 1; i < tab.n; ++i)
      if (bx >= tab.j[i].bx0) ji = i;
    mm_body(tab.j[ji], bx, smem);
    return;
  }
  float* att2s = smem;        // 128
  float* faws = smem + 128;   // 128
  float* es = smem + 256;     // 256 (196 used)
  float* red = smem + 512;    // 256
  int b = bx;
  if (tid < 128) {
    att2s[tid] = c.att2g1[b * 512 + tid] + c.dec_att_b[tid] + c.enc_att_b[tid];
    faws[tid] = c.full_att_w[tid];
    float g1v = fmaxf(c.att2g1[b * 512 + 128 + tid] + c.gate_b1[tid], 0.f);
    red[tid] = g1v * c.gate_w2[tid];
  } else {
    red[tid] = 0.f;
  }
  __syncthreads();
  for (int s = 128; s > 0; s >>= 1) {
    if (tid < s) red[tid] += red[tid + s];
    __syncthreads();
  }
  if (tid == 0) c.gate[b] = 1.f / (1.f + __expf(-(red[0] + c.gate_b2[0])));
  __syncthreads();
  int p = tid;
  float ev = -3.0e38f;
  if (p < P) {
    float acc = c.full_att_b[0];
    const float* a1p = c.att1 + (size_t)(b * P + p) * 128;
#pragma unroll 4
    for (int j = 0; j < 128; ++j) acc += fmaxf(a1p[j] + att2s[j], 0.f) * faws[j];
    es[p] = acc;
    ev = acc;
  }
  red[tid] = ev;
  __syncthreads();
  for (int s = 128; s > 0; s >>= 1) {
    if (tid < s) red[tid] = fmaxf(red[tid], red[tid + s]);
    __syncthreads();
  }
  float mx = red[0];
  __syncthreads();
  float ex = 0.f;
  if (p < P) ex = __expf(es[p] - mx);
  red[tid] = ex;
  __syncthreads();
  for (int s = 128; s > 0; s >>= 1) {
    if (tid < s) red[tid] += red[tid + s];
    __syncthreads();
  }
  float inv = 1.f / red[0];
  if (p < P) {
    float al = ex * inv;
    c.alpha[b * P + p] = al;
    if (c.t < c.declen[b]) c.out[OUT_ALPH + (size_t)(b * TSTEPS + c.t) * P + p] = al;
  }
}

// blocks 0..127: awe (+gate mult) -> gin[:,256:]; 128..143: x_t gather -> gin[:,0:256];
// 144..207: preds combine + masked store (step t-1)
__global__ __launch_bounds__(256) void awe_misc(Ctx c) {
  __shared__ float al[P];
  __shared__ float gs;
  int bx = blockIdx.x, tid = threadIdx.x;
  if (bx < 128) {
    int b = bx >> 1, ec = bx & 1;
    if (tid < P) al[tid] = c.alpha[b * P + tid];
    if (tid == 0) gs = c.gate[b];
    __syncthreads();
    int e = ec * 256 + tid;
    int ob = c.order_i[b];
    const float* ep = c.enc + (size_t)ob * P * ENCD + e;
    float acc = 0.f;
#pragma unroll 4
    for (int p = 0; p < P; ++p) acc += al[p] * ep[(size_t)p * ENCD];
    c.gin[b * 768 + 256 + e] = acc * gs;
  } else if (bx < 144) {
    int b = (bx - 128) * 4 + (tid >> 6);
    int cc = tid & 63;
    int tok = c.caps_s[b * MAXLEN + c.t];
    ((float4*)(c.gin + b * 768))[cc] = ((const float4*)(c.emb + (size_t)tok * EMBD))[cc];
  } else {
    int b = bx - 144;
    int tp = c.t - 1;
    if (tp >= 0 && tp < c.declen[b]) {
      for (int v = tid; v < VV; v += 256) {
        float s = c.fb2[v];
#pragma unroll
        for (int z = 0; z < 4; ++z) s += c.preds_p[(size_t)(z * 64 + b) * 2048 + v];
        c.out[OUT_PRED + (size_t)(b * TSTEPS + tp) * VV + v] = s;
      }
    }
  }
}

// GRU1 combine + residual proj + LN1; updates h1 (masked), writes h1res
__global__ __launch_bounds__(256) void combine1(Ctx c) {
  __shared__ float2 red[256];
  int b = blockIdx.x, tid = threadIdx.x;
  int m = (c.t < c.declen[b]) ? 1 : 0;
  float rv[2];
#pragma unroll
  for (int h = 0; h < 2; ++h) {
    int dd = tid + h * 256;
    float ir = c.bih1[dd], iz = c.bih1[512 + dd], ig = c.bih1[1024 + dd];
    float pj = c.proj_b[dd];
#pragma unroll
    for (int z = 0; z < 6; ++z) {
      const float* base = c.giP_p + (size_t)(z * 64 + b) * 2048;
      ir += base[dd]; iz += base[512 + dd]; ig += base[1024 + dd]; pj += base[1536 + dd];
    }
    float hr = c.bhh1[dd], hz = c.bhh1[512 + dd], hg = c.bhh1[1024 + dd];
#pragma unroll
    for (int z = 0; z < 4; ++z) {
      const float* base = c.gh1_p + (size_t)(z * 64 + b) * 1536;
      hr += base[dd]; hz += base[512 + dd]; hg += base[1024 + dd];
    }
    float r = 1.f / (1.f + __expf(-(ir + hr)));
    float zz = 1.f / (1.f + __expf(-(iz + hz)));
    float n = tanhf(ig + r * hg);
    float hold = c.h1[b * 512 + dd];
    float hnew = (1.f - zz) * n + zz * hold;
    c.h1[b * 512 + dd] = m ? hnew : hold;
    rv[h] = hnew + pj;
  }
  float2 pr;
  pr.x = rv[0] + rv[1];
  pr.y = rv[0] * rv[0] + rv[1] * rv[1];
  red[tid] = pr;
  __syncthreads();
  for (int s = 128; s > 0; s >>= 1) {
    if (tid < s) { red[tid].x += red[tid + s].x; red[tid].y += red[tid + s].y; }
    __syncthreads();
  }
  float mean = red[0].x * (1.f / 512.f);
  float var = red[0].y * (1.f / 512.f) - mean * mean;
  float inv = rsqrtf(var + 1e-5f);
#pragma unroll
  for (int h = 0; h < 2; ++h) {
    int dd = tid + h * 256;
    c.h1res[b * 512 + dd] = (rv[h] - mean) * inv * c.ln1g[dd] + c.ln1b[dd];
  }
}

// GRU2 combine + residual h1res + LN2; updates h2 (masked), writes h2res
__global__ __launch_bounds__(256) void combine2(Ctx c) {
  __shared__ float2 red[256];
  int b = blockIdx.x, tid = threadIdx.x;
  int m = (c.t < c.declen[b]) ? 1 : 0;
  float rv[2];
#pragma unroll
  for (int h = 0; h < 2; ++h) {
    int dd = tid + h * 256;
    float ir = c.bih2[dd], iz = c.bih2[512 + dd], ig = c.bih2[1024 + dd];
#pragma unroll
    for (int z = 0; z < 8; ++z) {
      const float* base = c.gi2_p + (size_t)(z * 64 + b) * 1536;
      ir += base[dd]; iz += base[512 + dd]; ig += base[1024 + dd];
    }
    float hr = c.bhh2[dd], hz = c.bhh2[512 + dd], hg = c.bhh2[1024 + dd];
#pragma unroll
    for (int z = 0; z < 4; ++z) {
      const float* base = c.gh2_p + (size_t)(z * 64 + b) * 1536;
      hr += base[dd]; hz += base[512 + dd]; hg += base[1024 + dd];
    }
    float r = 1.f / (1.f + __expf(-(ir + hr)));
    float zz = 1.f / (1.f + __expf(-(iz + hz)));
    float n = tanhf(ig + r * hg);
    float hold = c.h2[b * 512 + dd];
    float hnew = (1.f - zz) * n + zz * hold;
    c.h2[b * 512 + dd] = m ? hnew : hold;
    rv[h] = hnew + c.h1res[b * 512 + dd];
  }
  float2 pr;
  pr.x = rv[0] + rv[1];
  pr.y = rv[0] * rv[0] + rv[1] * rv[1];
  red[tid] = pr;
  __syncthreads();
  for (int s = 128; s > 0; s >>= 1) {
    if (tid < s) { red[tid].x += red[tid + s].x; red[tid].y += red[tid + s].y; }
    __syncthreads();
  }
  float mean = red[0].x * (1.f / 512.f);
  float var = red[0].y * (1.f / 512.f) - mean * mean;
  float inv = rsqrtf(var + 1e-5f);
#pragma unroll
  for (int h = 0; h < 2; ++h) {
    int dd = tid + h * 256;
    c.h2res[b * 512 + dd] = (rv[h] - mean) * inv * c.ln2g[dd] + c.ln2b[dd];
  }
}

// stable argsort(-len): rank = #{j : len[j]>len[i] or (len[j]==len[i] and j<i)}
__global__ void k_order(Ctx c) {
  __shared__ int lens[B];
  int tid = threadIdx.x;
  lens[tid] = c.lens_in[tid];
  __syncthreads();
  int li = lens[tid];
  int pos = 0;
  for (int j = 0; j < B; ++j) {
    int lj = lens[j];
    pos += (lj > li || (lj == li && j < tid)) ? 1 : 0;
  }
  c.order_i[pos] = tid;
  c.declen[pos] = li - 1;
  c.out[OUT_ORDR + pos] = (float)tid;
  c.out[OUT_DECL + pos] = (float)(li - 1);
}

__global__ __launch_bounds__(256) void k_caps(Ctx c) {
  int idx = blockIdx.x * 256 + threadIdx.x;
  if (idx < B * MAXLEN) {
    int b = idx / MAXLEN, t = idx % MAXLEN;
    int v = c.caps_in[c.order_i[b] * MAXLEN + t];
    c.caps_s[idx] = v;
    c.out[OUT_CAPS + idx] = (float)v;
  }
}

__global__ __launch_bounds__(256) void k_transpose(const float* W, float* Wt, int D, int K, int Dld, int doff) {
  int total = D * K;
  for (int idx = blockIdx.x * 256 + threadIdx.x; idx < total; idx += gridDim.x * 256) {
    int k = idx / D;
    int d = idx - k * D;
    Wt[(size_t)k * Dld + doff + d] = W[(size_t)d * K + k];
  }
}

// att1[b*P+p][j] = sum_k enc[order[b], p, k] * enc_att_w[j, k]  (no bias; folded into att2s)
__global__ __launch_bounds__(256) void k_att1(Ctx c) {
  __shared__ float Xs[8 * 512];
  int tid = threadIdx.x;
  int r0 = blockIdx.x * 8;
  for (int idx = tid; idx < 8 * 512; idx += 256) {
    int rr = idx >> 9, k = idx & 511;
    int r = r0 + rr;
    int b = r / P, p = r - b * P;
    int ob = c.order_i[b];
    Xs[idx] = c.enc[((size_t)(ob * P + p)) * ENCD + k];
  }
  __syncthreads();
  int d = tid >> 1, kh = tid & 1;
  float acc[8];
#pragma unroll
  for (int rr = 0; rr < 8; ++rr) acc[rr] = 0.f;
  int kbase = kh * 256;
  for (int k = 0; k < 256; ++k) {
    float w = c.EaT[(size_t)(kbase + k) * 128 + d];
#pragma unroll
    for (int rr = 0; rr < 8; ++rr) acc[rr] += w * Xs[rr * 512 + kbase + k];
  }
#pragma unroll
  for (int rr = 0; rr < 8; ++rr) {
    acc[rr] += __shfl_xor(acc[rr], 1);
    if (kh == 0) c.att1[(size_t)(r0 + rr) * 128 + d] = acc[rr];
  }
}

extern "C" void kernel_launch(void* const* d_in, const int* in_sizes, int n_in,
                              void* d_out, int out_size, void* d_ws, size_t ws_size,
                              hipStream_t stream) {
  (void)in_sizes; (void)n_in; (void)ws_size;
  Ctx c;
  c.enc = (const float*)d_in[0];
  c.caps_in = (const int*)d_in[1];
  c.lens_in = (const int*)d_in[2];
  const float* enc_att_w = (const float*)d_in[3];
  c.enc_att_b = (const float*)d_in[4];
  const float* dec_att_w = (const float*)d_in[5];
  c.dec_att_b = (const float*)d_in[6];
  c.full_att_w = (const float*)d_in[7];
  c.full_att_b = (const float*)d_in[8];
  const float* gate_w1 = (const float*)d_in[9];
  c.gate_b1 = (const float*)d_in[10];
  c.gate_w2 = (const float*)d_in[11];
  c.gate_b2 = (const float*)d_in[12];
  c.emb = (const float*)d_in[13];
  const float* w_ih1 = (const float*)d_in[14];
  const float* w_hh1 = (const float*)d_in[15];
  c.bih1 = (const float*)d_in[16];
  c.bhh1 = (const float*)d_in[17];
  const float* w_ih2 = (const float*)d_in[18];
  const float* w_hh2 = (const float*)d_in[19];
  c.bih2 = (const float*)d_in[20];
  c.bhh2 = (const float*)d_in[21];
  const float* proj_w = (const float*)d_in[22];
  c.proj_b = (const float*)d_in[23];
  c.ln1g = (const float*)d_in[24];
  c.ln1b = (const float*)d_in[25];
  c.ln2g = (const float*)d_in[26];
  c.ln2b = (const float*)d_in[27];
  const float* ffn_w1 = (const float*)d_in[28];
  c.fb1 = (const float*)d_in[29];
  const float* ffn_w2 = (const float*)d_in[30];
  c.fb2 = (const float*)d_in[31];
  c.out = (float*)d_out;

  char* wp_ = (char*)d_ws;
  auto alloc = [&](size_t bytes) -> char* {
    char* p = wp_;
    wp_ += (bytes + 255) & ~(size_t)255;
    return p;
  };
  c.order_i = (int*)alloc(B * 4);
  c.declen = (int*)alloc(B * 4);
  c.caps_s = (int*)alloc((size_t)B * MAXLEN * 4);
  float* WtA = (float*)alloc((size_t)512 * 512 * 4);
  float* Whh1T = (float*)alloc((size_t)512 * 1536 * 4);
  float* Whh2T = (float*)alloc((size_t)512 * 1536 * 4);
  float* WipT = (float*)alloc((size_t)768 * 2048 * 4);
  float* Wih2T = (float*)alloc((size_t)512 * 1536 * 4);
  float* F1T = (float*)alloc((size_t)512 * 1024 * 4);
  float* F2T = (float*)alloc((size_t)1024 * 2048 * 4);
  c.EaT = (float*)alloc((size_t)512 * 128 * 4);
  c.att1 = (float*)alloc((size_t)B * P * 128 * 4);
  float* states = (float*)alloc((size_t)4 * B * 512 * 4);
  c.h1 = states;
  c.h2 = states + B * 512;
  c.h2res = states + 2 * B * 512;
  c.h1res = states + 3 * B * 512;
  c.att2g1 = (float*)alloc((size_t)B * 512 * 4);
  c.gate = (float*)alloc(B * 4);
  c.alpha = (float*)alloc((size_t)B * P * 4);
  c.gin = (float*)alloc((size_t)B * 768 * 4);
  c.f_p = (float*)alloc((size_t)2 * B * 1024 * 4);
  c.preds_p = (float*)alloc((size_t)4 * B * 2048 * 4);
  c.gh1_p = (float*)alloc((size_t)4 * B * 1536 * 4);
  c.gh2_p = (float*)alloc((size_t)4 * B * 1536 * 4);
  c.giP_p = (float*)alloc((size_t)6 * B * 2048 * 4);
  c.gi2_p = (float*)alloc((size_t)8 * B * 1536 * 4);

  hipMemsetAsync(d_out, 0, (size_t)out_size * 4, stream);
  hipMemsetAsync(states, 0, (size_t)4 * B * 512 * 4, stream);

  c.t = 0;
  k_order<<<1, 64, 0, stream>>>(c);
  k_caps<<<(B * MAXLEN + 255) / 256, 256, 0, stream>>>(c);

  auto tgrid = [](int D, int K) { int g = (D * K + 255) / 256; return g > 2048 ? 2048 : g; };
  k_transpose<<<tgrid(128, 512), 256, 0, stream>>>(dec_att_w, WtA, 128, 512, 512, 0);
  k_transpose<<<tgrid(128, 512), 256, 0, stream>>>(gate_w1, WtA, 128, 512, 512, 128);
  k_transpose<<<tgrid(1536, 512), 256, 0, stream>>>(w_hh1, Whh1T, 1536, 512, 1536, 0);
  k_transpose<<<tgrid(1536, 512), 256, 0, stream>>>(w_hh2, Whh2T, 1536, 512, 1536, 0);
  k_transpose<<<tgrid(1536, 768), 256, 0, stream>>>(w_ih1, WipT, 1536, 768, 2048, 0);
  k_transpose<<<tgrid(512, 768), 256, 0, stream>>>(proj_w, WipT, 512, 768, 2048, 1536);
  k_transpose<<<tgrid(1536, 512), 256, 0, stream>>>(w_ih2, Wih2T, 1536, 512, 1536, 0);
  k_transpose<<<tgrid(1024, 512), 256, 0, stream>>>(ffn_w1, F1T, 1024, 512, 1024, 0);
  k_transpose<<<tgrid(2000, 1024), 256, 0, stream>>>(ffn_w2, F2T, 2000, 1024, 2048, 0);
  k_transpose<<<tgrid(128, 512), 256, 0, stream>>>(enc_att_w, c.EaT, 128, 512, 128, 0);

  k_att1<<<(B * P) / 8, 256, 0, stream>>>(c);

  auto mkjob = [](const float* X, const float* Xaux, const float* Wt, float* outp,
                  int Dld, int Kstr, int k0, int kcl, int bx0, int nbx, int mode) {
    MMJob j;
    j.X = X; j.Xaux = Xaux; j.Wt = Wt; j.outp = outp;
    j.Dld = Dld; j.Kstr = Kstr; j.k0 = k0; j.kcl = kcl; j.bx0 = bx0; j.nbx = nbx; j.mode = mode;
    return j;
  };

  // Launch A: gh1(4 ksplits), gh2(4), att2g1, f (2 ksplits, from h2res of t-1)
  MMTable tabA;
  tabA.n = 11;
  int bxc = 0;
  for (int z = 0; z < 4; ++z) { tabA.j[z] = mkjob(c.h1, nullptr, Whh1T, c.gh1_p + (size_t)z * B * 1536, 1536, 512, z * 128, 7, bxc, 3, 0); bxc += 24; }
  for (int z = 0; z < 4; ++z) { tabA.j[4 + z] = mkjob(c.h2, nullptr, Whh2T, c.gh2_p + (size_t)z * B * 1536, 1536, 512, z * 128, 7, bxc, 3, 0); bxc += 24; }
  tabA.j[8] = mkjob(c.h2, nullptr, WtA, c.att2g1, 512, 512, 0, 9, bxc, 1, 0); bxc += 8;
  for (int z = 0; z < 2; ++z) { tabA.j[9 + z] = mkjob(c.h2res, nullptr, F1T, c.f_p + (size_t)z * B * 1024, 1024, 512, z * 256, 8, bxc, 2, 0); bxc += 16; }
  const int gridA = bxc;  // 232

  // Launch B: blocks 0..63 attn; preds partials (mode1 X-stage: relu(f_p0+f_p1+b1))
  MMTable tabB;
  tabB.n = 4;
  bxc = 64;
  for (int z = 0; z < 4; ++z) { tabB.j[z] = mkjob(c.f_p, c.fb1, F2T, c.preds_p + (size_t)z * B * 2048, 2048, 1024, z * 256, 8, bxc, 4, 1); bxc += 32; }
  const int gridB = bxc;  // 192

  // Launch D: giP = gin @ [wih1|proj]^T, 6 ksplits
  MMTable tabD;
  tabD.n = 6;
  bxc = 0;
  for (int z = 0; z < 6; ++z) { tabD.j[z] = mkjob(c.gin, nullptr, WipT, c.giP_p + (size_t)z * B * 2048, 2048, 768, z * 128, 7, bxc, 4, 0); bxc += 32; }
  const int gridD = bxc;  // 192

  // Launch F: gi2 = h1res @ wih2^T, 8 ksplits
  MMTable tabF;
  tabF.n = 8;
  bxc = 0;
  for (int z = 0; z < 8; ++z) { tabF.j[z] = mkjob(c.h1res, nullptr, Wih2T, c.gi2_p + (size_t)z * B * 1536, 1536, 512, z * 64, 6, bxc, 3, 0); bxc += 24; }
  const int gridF = bxc;  // 192

  for (int t = 0; t <= TSTEPS; ++t) {  // t==159 iteration only flushes the final FFN
    c.t = t;
    mm_phase<<<gridA, 256, 16384, stream>>>(tabA);
    attn_preds<<<gridB, 256, 8192, stream>>>(c, tabB);
    awe_misc<<<208, 256, 0, stream>>>(c);
    if (t < TSTEPS) {
      mm_phase<<<gridD, 256, 4096, stream>>>(tabD);
      combine1<<<64, 256, 0, stream>>>(c);
      mm_phase<<<gridF, 256, 2048, stream>>>(tabF);
      combine2<<<64, 256, 0, stream>>>(c);
    }
  }
}